// Round 2
// baseline (177.626 us; speedup 1.0000x reference)
//
#include <hip/hip_runtime.h>
#include <hip/hip_bf16.h>

// Problem constants (fixed by the reference model definition)
#define PAD        14
#define ACD        32
#define ATD        8
#define RCD        32
#define RID        32
#define N_CODES    38
#define N_TYPES    6
#define N_RES      21
#define MAX_SEQ    1024
#define IN0        624     // PAD*ACD + PAD*ATD + RCD + RID
#define OUT0       128
#define OUT1       32      // y1 channels (x3 coords = 96)
#define FEAT       224     // 128 + 96

__device__ __constant__ const float NORM0 = 0.04003203845f;  // 1/sqrt(624)
__device__ __constant__ const float NORM1 = 0.26726124191f;  // 1/sqrt(14)

// ws float offsets
#define OFF_TCODE  0
#define SZ_TCODE   (PAD * N_CODES * OUT0)          // 68096
#define OFF_TTYPE  (OFF_TCODE + SZ_TCODE)
#define SZ_TTYPE   (PAD * N_TYPES * OUT0)          // 10752
#define OFF_TRC    (OFF_TTYPE + SZ_TTYPE)
#define SZ_TRC     (N_RES * OUT0)                  // 2688
#define OFF_TRI    (OFF_TRC + SZ_TRC)
#define SZ_TRI     (MAX_SEQ * OUT0)                // 131072
#define OFF_STARTS (OFF_TRI + SZ_TRI)              // 212608 (ints from here)

// ---------------------------------------------------------------------------
// Kernel 1: per-residue start offsets (atoms are sorted by residue, count>=1)
__global__ void build_starts(const int* __restrict__ resIdx, int n_atoms,
                             int* __restrict__ starts) {
    int i = blockIdx.x * blockDim.x + threadIdx.x;
    if (i >= n_atoms) return;
    int r = resIdx[i];
    if (i == 0 || resIdx[i - 1] != r) starts[r] = i;
}

// ---------------------------------------------------------------------------
// Kernel 2: fold W0 through the embedding tables (with 1/sqrt(624) folded in).
// Rows: [0,532) Tcode(m,c) | [532,616) Ttype(m,t) | [616,637) Trc(c) | [637,1661) Tri(s)
__global__ void build_tables(const float* __restrict__ act, const float* __restrict__ att,
                             const float* __restrict__ rct, const float* __restrict__ rit,
                             const float* __restrict__ W0,
                             float* __restrict__ Tcode, float* __restrict__ Ttype,
                             float* __restrict__ Trc,   float* __restrict__ Tri) {
    int b = blockIdx.x;
    int o = threadIdx.x;  // 128 output channels
    float acc = 0.f;
    if (b < PAD * N_CODES) {
        int m = b / N_CODES, c = b % N_CODES;
        const float* a = act + c * ACD;
        const float* w = W0 + (size_t)(m * ACD) * OUT0 + o;
#pragma unroll
        for (int j = 0; j < ACD; ++j) acc += a[j] * w[(size_t)j * OUT0];
        Tcode[(size_t)b * OUT0 + o] = acc * NORM0;
    } else if (b < PAD * N_CODES + PAD * N_TYPES) {
        int t = b - PAD * N_CODES;
        int m = t / N_TYPES, ty = t % N_TYPES;
        const float* a = att + ty * ATD;
        const float* w = W0 + (size_t)(PAD * ACD + m * ATD) * OUT0 + o;
#pragma unroll
        for (int j = 0; j < ATD; ++j) acc += a[j] * w[(size_t)j * OUT0];
        Ttype[(size_t)t * OUT0 + o] = acc * NORM0;
    } else if (b < PAD * N_CODES + PAD * N_TYPES + N_RES) {
        int c = b - (PAD * N_CODES + PAD * N_TYPES);
        const float* a = rct + c * RCD;
        const float* w = W0 + (size_t)(PAD * ACD + PAD * ATD) * OUT0 + o;
#pragma unroll
        for (int j = 0; j < RCD; ++j) acc += a[j] * w[(size_t)j * OUT0];
        Trc[(size_t)c * OUT0 + o] = acc * NORM0;
    } else {
        int s = b - (PAD * N_CODES + PAD * N_TYPES + N_RES);
        const float* a = rit + s * RID;
        const float* w = W0 + (size_t)(PAD * ACD + PAD * ATD + RCD) * OUT0 + o;
#pragma unroll
        for (int j = 0; j < RID; ++j) acc += a[j] * w[(size_t)j * OUT0];
        Tri[(size_t)s * OUT0 + o] = acc * NORM0;
    }
}

// ---------------------------------------------------------------------------
// Kernel 3: main. One wave (64 lanes) per residue; 4 residues per 256-block.
// y0: float2 per lane (channels 2*lane, 2*lane+1) accumulated from projected
//     table rows (coalesced 512B reads from L2-resident tables).
// y1: lanes 0..47 each own two of the 96 outputs k = n*3+c; W1*NORM1 in LDS.
__global__ __launch_bounds__(256) void main_kernel(
    const float*  __restrict__ coords,   // [n_atoms,3]
    const int*    __restrict__ codeIdx,  // [n_atoms]
    const int*    __restrict__ typeIdx,  // [n_atoms]
    const int*    __restrict__ counts,   // [R]
    const int*    __restrict__ rcIdx,    // [R]
    const int*    __restrict__ rsIdx,    // [R]
    const float*  __restrict__ baseIn,   // [R,3]
    const float*  __restrict__ W1,       // [14,32]
    const float*  __restrict__ Tcode, const float* __restrict__ Ttype,
    const float*  __restrict__ Trc,   const float* __restrict__ Tri,
    const int*    __restrict__ starts,
    float* __restrict__ outBase, float* __restrict__ outFeat, int R) {
    __shared__ float w1s[PAD * OUT1];
    for (int i = threadIdx.x; i < PAD * OUT1; i += 256) w1s[i] = W1[i] * NORM1;
    __syncthreads();

    int wid  = threadIdx.x >> 6;
    int lane = threadIdx.x & 63;
    int r = blockIdx.x * 4 + wid;
    if (r >= R) return;

    int start = starts[r];
    int cnt   = counts[r];

    if (lane < 3) outBase[(size_t)r * 3 + lane] = baseIn[(size_t)r * 3 + lane];

    // preload this residue's atoms across lanes
    int   codev = 0, typev = 0;
    float cxv = 0.f, cyv = 0.f, czv = 0.f;
    if (lane < cnt) {
        int a = start + lane;
        codev = codeIdx[a];
        typev = typeIdx[a];
        cxv = coords[(size_t)a * 3 + 0];
        cyv = coords[(size_t)a * 3 + 1];
        czv = coords[(size_t)a * 3 + 2];
    }

    const float2* Tcode2 = reinterpret_cast<const float2*>(Tcode);
    const float2* Ttype2 = reinterpret_cast<const float2*>(Ttype);
    const float2* Trc2   = reinterpret_cast<const float2*>(Trc);
    const float2* Tri2   = reinterpret_cast<const float2*>(Tri);

    int rc = rcIdx[r], rs = rsIdx[r];
    float2 acc = Trc2[(size_t)rc * 64 + lane];
    float2 tri = Tri2[(size_t)rs * 64 + lane];
    acc.x += tri.x; acc.y += tri.y;

    // y1 bookkeeping: lane handles flat outputs k0=2*lane, k1=2*lane+1 (k<96)
    bool doY1 = lane < 48;
    int  k0 = 2 * lane, k1 = k0 + 1;
    int  n0 = doY1 ? (k0 / 3) : 0, c0 = doY1 ? (k0 % 3) : 0;
    int  n1 = doY1 ? (k1 / 3) : 0, c1 = doY1 ? (k1 % 3) : 0;
    float v0 = 0.f, v1 = 0.f;

    for (int m = 0; m < cnt; ++m) {
        int cd = __shfl(codev, m);
        int tp = __shfl(typev, m);
        float2 tc = Tcode2[(size_t)(m * N_CODES + cd) * 64 + lane];
        float2 tt = Ttype2[(size_t)(m * N_TYPES + tp) * 64 + lane];
        acc.x += tc.x + tt.x;
        acc.y += tc.y + tt.y;
        float cx = __shfl(cxv, m), cy = __shfl(cyv, m), cz = __shfl(czv, m);
        if (doY1) {
            float w0 = w1s[m * OUT1 + n0];
            float w1 = w1s[m * OUT1 + n1];
            float p0 = (c0 == 0) ? cx : ((c0 == 1) ? cy : cz);
            float p1 = (c1 == 0) ? cx : ((c1 == 1) ? cy : cz);
            v0 = fmaf(p0, w0, v0);
            v1 = fmaf(p1, w1, v1);
        }
    }

    float* fo = outFeat + (size_t)r * FEAT;
    reinterpret_cast<float2*>(fo)[lane] = acc;          // channels 0..127
    if (doY1) {
        *reinterpret_cast<float2*>(fo + OUT0 + k0) = make_float2(v0, v1);  // 128..223
    }
}

// ---------------------------------------------------------------------------
// Fallback (ws too small): direct per-residue dense dot, binary-search starts.
__global__ __launch_bounds__(128) void fallback_kernel(
    const float* __restrict__ coords, const int* __restrict__ codeIdx,
    const int* __restrict__ typeIdx, const int* __restrict__ resIdx,
    const int* __restrict__ counts, const int* __restrict__ rcIdx,
    const int* __restrict__ rsIdx, const float* __restrict__ baseIn,
    const float* __restrict__ act, const float* __restrict__ att,
    const float* __restrict__ rct, const float* __restrict__ rit,
    const float* __restrict__ W0, const float* __restrict__ W1,
    float* __restrict__ outBase, float* __restrict__ outFeat, int R, int n_atoms) {
    int r = blockIdx.x, tid = threadIdx.x;
    __shared__ float s[IN0];
    __shared__ int sh_start;
    if (tid == 0) {
        int lo = 0, hi = n_atoms;
        while (lo < hi) { int mid = (lo + hi) >> 1; if (resIdx[mid] < r) lo = mid + 1; else hi = mid; }
        sh_start = lo;
    }
    __syncthreads();
    int start = sh_start, cnt = counts[r];
    for (int j = tid; j < IN0; j += 128) {
        float v = 0.f;
        if (j < PAD * ACD) {
            int m = j >> 5, jj = j & 31;
            if (m < cnt) v = act[codeIdx[start + m] * ACD + jj];
        } else if (j < PAD * ACD + PAD * ATD) {
            int t = j - PAD * ACD; int m = t >> 3, jj = t & 7;
            if (m < cnt) v = att[typeIdx[start + m] * ATD + jj];
        } else if (j < PAD * ACD + PAD * ATD + RCD) {
            v = rct[rcIdx[r] * RCD + (j - PAD * ACD - PAD * ATD)];
        } else {
            v = rit[rsIdx[r] * RID + (j - PAD * ACD - PAD * ATD - RCD)];
        }
        s[j] = v;
    }
    __syncthreads();
    float accv = 0.f;
    for (int j = 0; j < IN0; ++j) accv += s[j] * W0[(size_t)j * OUT0 + tid];
    float* fo = outFeat + (size_t)r * FEAT;
    fo[tid] = accv * NORM0;
    if (tid < 96) {
        int n = tid / 3, c = tid % 3;
        float v = 0.f;
        for (int m = 0; m < cnt; ++m) v += coords[(size_t)(start + m) * 3 + c] * W1[m * OUT1 + n];
        fo[OUT0 + tid] = v * NORM1;
    }
    if (tid < 3) outBase[(size_t)r * 3 + tid] = baseIn[(size_t)r * 3 + tid];
}

// ---------------------------------------------------------------------------
extern "C" void kernel_launch(void* const* d_in, const int* in_sizes, int n_in,
                              void* d_out, int out_size, void* d_ws, size_t ws_size,
                              hipStream_t stream) {
    const float* coords = (const float*)d_in[0];
    const int*   codeIdx = (const int*)d_in[1];
    const int*   typeIdx = (const int*)d_in[2];
    const int*   resIdx  = (const int*)d_in[3];
    const int*   counts  = (const int*)d_in[4];
    const int*   rcIdx   = (const int*)d_in[5];
    const int*   rsIdx   = (const int*)d_in[6];
    const float* baseIn  = (const float*)d_in[7];
    const float* act     = (const float*)d_in[8];
    const float* att     = (const float*)d_in[9];
    const float* rct     = (const float*)d_in[10];
    const float* rit     = (const float*)d_in[11];
    const float* W0      = (const float*)d_in[12];
    const float* W1      = (const float*)d_in[13];

    int n_atoms = in_sizes[1];
    int R       = in_sizes[4];

    float* out     = (float*)d_out;
    float* outBase = out;
    float* outFeat = out + (size_t)R * 3;

    size_t need_bytes = (size_t)(OFF_STARTS + R) * 4;
    if (ws_size >= need_bytes) {
        float* ws     = (float*)d_ws;
        float* Tcode  = ws + OFF_TCODE;
        float* Ttype  = ws + OFF_TTYPE;
        float* Trc    = ws + OFF_TRC;
        float* Tri    = ws + OFF_TRI;
        int*   starts = (int*)(ws + OFF_STARTS);

        build_starts<<<(n_atoms + 255) / 256, 256, 0, stream>>>(resIdx, n_atoms, starts);
        int nrows = PAD * N_CODES + PAD * N_TYPES + N_RES + MAX_SEQ;  // 1661
        build_tables<<<nrows, OUT0, 0, stream>>>(act, att, rct, rit, W0, Tcode, Ttype, Trc, Tri);
        main_kernel<<<(R + 3) / 4, 256, 0, stream>>>(
            coords, codeIdx, typeIdx, counts, rcIdx, rsIdx, baseIn, W1,
            Tcode, Ttype, Trc, Tri, starts, outBase, outFeat, R);
    } else {
        fallback_kernel<<<R, 128, 0, stream>>>(
            coords, codeIdx, typeIdx, resIdx, counts, rcIdx, rsIdx, baseIn,
            act, att, rct, rit, W0, W1, outBase, outFeat, R, n_atoms);
    }
}

// Round 3
// 152.772 us; speedup vs baseline: 1.1627x; 1.1627x over previous
//
#include <hip/hip_runtime.h>
#include <hip/hip_bf16.h>

// Problem constants (fixed by the reference model definition)
#define PAD        14
#define ACD        32
#define ATD        8
#define RCD        32
#define RID        32
#define N_CODES    38
#define N_TYPES    6
#define NCT        (N_CODES * N_TYPES)   // 228 combined code*6+type rows per slot
#define N_RES      21
#define MAX_SEQ    1024
#define IN0        624     // PAD*ACD + PAD*ATD + RCD + RID
#define OUT0       128
#define OUT1       32      // y1 channels (x3 coords = 96)
#define FEAT       224     // 128 + 96

__device__ __constant__ const float NORM0 = 0.04003203845f;  // 1/sqrt(624)
__device__ __constant__ const float NORM1 = 0.26726124191f;  // 1/sqrt(14)

typedef float f32x2 __attribute__((ext_vector_type(2)));

// ws float offsets
#define SZ_TCT     (PAD * NCT * OUT0)              // 408576 (1.63 MB, L2-resident)
#define OFF_TCT    0
#define OFF_TRC    (OFF_TCT + SZ_TCT)
#define SZ_TRC     (N_RES * OUT0)                  // 2688
#define OFF_TRI    (OFF_TRC + SZ_TRC)
#define SZ_TRI     (MAX_SEQ * OUT0)                // 131072
#define OFF_STARTS (OFF_TRI + SZ_TRI)              // ints from here

// ---------------------------------------------------------------------------
// Kernel 1: per-residue start offsets (atoms sorted by residue, count>=1)
__global__ void build_starts(const int* __restrict__ resIdx, int n_atoms,
                             int* __restrict__ starts) {
    int i = blockIdx.x * blockDim.x + threadIdx.x;
    if (i >= n_atoms) return;
    int r = resIdx[i];
    if (i == 0 || resIdx[i - 1] != r) starts[r] = i;
}

// ---------------------------------------------------------------------------
// Kernel 2: fold W0 through the embedding tables, NORM0 included.
// Combined code+type table: Tct[m][code*6+type][o] = (emb_c@W0_m + emb_t@W0_m').
// Rows: [0,3192) Tct | [3192,3213) Trc | [3213,4237) Tri
__global__ void build_tables(const float* __restrict__ act, const float* __restrict__ att,
                             const float* __restrict__ rct, const float* __restrict__ rit,
                             const float* __restrict__ W0,
                             float* __restrict__ Tct, float* __restrict__ Trc,
                             float* __restrict__ Tri) {
    int b = blockIdx.x;
    int o = threadIdx.x;  // 128 output channels (coalesced W0 column reads)
    float acc = 0.f;
    if (b < PAD * NCT) {
        int m = b / NCT, ct = b % NCT, c = ct / N_TYPES, t = ct % N_TYPES;
        const float* wc = W0 + (size_t)(m * ACD) * OUT0 + o;
        const float* wt = W0 + (size_t)(PAD * ACD + m * ATD) * OUT0 + o;
#pragma unroll
        for (int j = 0; j < ACD; ++j) acc += act[c * ACD + j] * wc[(size_t)j * OUT0];
#pragma unroll
        for (int j = 0; j < ATD; ++j) acc += att[t * ATD + j] * wt[(size_t)j * OUT0];
        Tct[(size_t)b * OUT0 + o] = acc * NORM0;
    } else if (b < PAD * NCT + N_RES) {
        int c = b - PAD * NCT;
        const float* w = W0 + (size_t)(PAD * ACD + PAD * ATD) * OUT0 + o;
#pragma unroll
        for (int j = 0; j < RCD; ++j) acc += rct[c * RCD + j] * w[(size_t)j * OUT0];
        Trc[(size_t)c * OUT0 + o] = acc * NORM0;
    } else {
        int s = b - (PAD * NCT + N_RES);
        const float* w = W0 + (size_t)(PAD * ACD + PAD * ATD + RCD) * OUT0 + o;
#pragma unroll
        for (int j = 0; j < RID; ++j) acc += rit[s * RID + j] * w[(size_t)j * OUT0];
        Tri[(size_t)s * OUT0 + o] = acc * NORM0;
    }
}

// ---------------------------------------------------------------------------
// Kernel 3: main. One wave per residue, 4 waves/block, NO LDS, no shuffles.
// All per-residue/per-atom metadata is wave-uniform (SGPR loads). y0: float2
// per lane from the combined table (one 512B coalesced row read per atom).
// y1: lanes 0..31 own output n=lane, accumulate all 3 coords. NT stores keep
// the 181MB output stream from evicting the L2-resident tables.
__global__ __launch_bounds__(256) void main_kernel(
    const float*  __restrict__ coords,   // [n_atoms,3]
    const int*    __restrict__ codeIdx,  // [n_atoms]
    const int*    __restrict__ typeIdx,  // [n_atoms]
    const int*    __restrict__ counts,   // [R]
    const int*    __restrict__ rcIdx,    // [R]
    const int*    __restrict__ rsIdx,    // [R]
    const float*  __restrict__ baseIn,   // [R,3]
    const float*  __restrict__ W1,       // [14,32]
    const float*  __restrict__ Tct, const float* __restrict__ Trc,
    const float*  __restrict__ Tri, const int* __restrict__ starts,
    float* __restrict__ outBase, float* __restrict__ outFeat, int R) {
    int wid  = threadIdx.x >> 6;
    int lane = threadIdx.x & 63;
    int r = __builtin_amdgcn_readfirstlane(blockIdx.x * 4 + wid);
    if (r >= R) return;

    int start = starts[r];          // wave-uniform -> SMEM
    int cnt   = counts[r];
    int lane32 = lane & 31;

    // base_coords passthrough (12B per residue)
    if (lane < 3) {
        __builtin_nontemporal_store(baseIn[(size_t)r * 3 + lane],
                                    &outBase[(size_t)r * 3 + lane]);
    }

    const f32x2* Tct2 = reinterpret_cast<const f32x2*>(Tct);
    const f32x2* Trc2 = reinterpret_cast<const f32x2*>(Trc);
    const f32x2* Tri2 = reinterpret_cast<const f32x2*>(Tri);

    int rc = rcIdx[r], rs = rsIdx[r];
    f32x2 a0 = Trc2[(size_t)rc * 64 + lane];
    f32x2 a1 = Tri2[(size_t)rs * 64 + lane];
    float acx = a0.x + a1.x;
    float acy = a0.y + a1.y;
    float vx = 0.f, vy = 0.f, vz = 0.f;

#pragma unroll
    for (int m = 0; m < PAD; ++m) {
        if (m >= 4 && m >= cnt) break;   // cnt >= 4 always; uniform scalar branch
        int a  = start + m;              // all wave-uniform (SMEM loads)
        int cd = codeIdx[a];
        int tp = typeIdx[a];
        f32x2 t = Tct2[(size_t)(m * NCT + cd * N_TYPES + tp) * 64 + lane];
        float cx = coords[(size_t)a * 3 + 0];
        float cy = coords[(size_t)a * 3 + 1];
        float cz = coords[(size_t)a * 3 + 2];
        float w  = W1[m * OUT1 + lane32] * NORM1;   // 128B L1-hot row read
        acx += t.x; acy += t.y;
        vx = fmaf(cx, w, vx);
        vy = fmaf(cy, w, vy);
        vz = fmaf(cz, w, vz);
    }

    float* fo = outFeat + (size_t)r * FEAT;
    f32x2 accv; accv.x = acx; accv.y = acy;
    __builtin_nontemporal_store(accv, reinterpret_cast<f32x2*>(fo) + lane);  // ch 0..127
    if (lane < 32) {
        float* p = fo + OUT0 + 3 * lane32;   // ch 128..223, contiguous across lanes
        __builtin_nontemporal_store(vx, p + 0);
        __builtin_nontemporal_store(vy, p + 1);
        __builtin_nontemporal_store(vz, p + 2);
    }
}

// ---------------------------------------------------------------------------
// Fallback (ws too small): direct per-residue dense dot, binary-search starts.
__global__ __launch_bounds__(128) void fallback_kernel(
    const float* __restrict__ coords, const int* __restrict__ codeIdx,
    const int* __restrict__ typeIdx, const int* __restrict__ resIdx,
    const int* __restrict__ counts, const int* __restrict__ rcIdx,
    const int* __restrict__ rsIdx, const float* __restrict__ baseIn,
    const float* __restrict__ act, const float* __restrict__ att,
    const float* __restrict__ rct, const float* __restrict__ rit,
    const float* __restrict__ W0, const float* __restrict__ W1,
    float* __restrict__ outBase, float* __restrict__ outFeat, int R, int n_atoms) {
    int r = blockIdx.x, tid = threadIdx.x;
    __shared__ float s[IN0];
    __shared__ int sh_start;
    if (tid == 0) {
        int lo = 0, hi = n_atoms;
        while (lo < hi) { int mid = (lo + hi) >> 1; if (resIdx[mid] < r) lo = mid + 1; else hi = mid; }
        sh_start = lo;
    }
    __syncthreads();
    int start = sh_start, cnt = counts[r];
    for (int j = tid; j < IN0; j += 128) {
        float v = 0.f;
        if (j < PAD * ACD) {
            int m = j >> 5, jj = j & 31;
            if (m < cnt) v = act[codeIdx[start + m] * ACD + jj];
        } else if (j < PAD * ACD + PAD * ATD) {
            int t = j - PAD * ACD; int m = t >> 3, jj = t & 7;
            if (m < cnt) v = att[typeIdx[start + m] * ATD + jj];
        } else if (j < PAD * ACD + PAD * ATD + RCD) {
            v = rct[rcIdx[r] * RCD + (j - PAD * ACD - PAD * ATD)];
        } else {
            v = rit[rsIdx[r] * RID + (j - PAD * ACD - PAD * ATD - RCD)];
        }
        s[j] = v;
    }
    __syncthreads();
    float accv = 0.f;
    for (int j = 0; j < IN0; ++j) accv += s[j] * W0[(size_t)j * OUT0 + tid];
    float* fo = outFeat + (size_t)r * FEAT;
    fo[tid] = accv * NORM0;
    if (tid < 96) {
        int n = tid / 3, c = tid % 3;
        float v = 0.f;
        for (int m = 0; m < cnt; ++m) v += coords[(size_t)(start + m) * 3 + c] * W1[m * OUT1 + n];
        fo[OUT0 + tid] = v * NORM1;
    }
    if (tid < 3) outBase[(size_t)r * 3 + tid] = baseIn[(size_t)r * 3 + tid];
}

// ---------------------------------------------------------------------------
extern "C" void kernel_launch(void* const* d_in, const int* in_sizes, int n_in,
                              void* d_out, int out_size, void* d_ws, size_t ws_size,
                              hipStream_t stream) {
    const float* coords = (const float*)d_in[0];
    const int*   codeIdx = (const int*)d_in[1];
    const int*   typeIdx = (const int*)d_in[2];
    const int*   resIdx  = (const int*)d_in[3];
    const int*   counts  = (const int*)d_in[4];
    const int*   rcIdx   = (const int*)d_in[5];
    const int*   rsIdx   = (const int*)d_in[6];
    const float* baseIn  = (const float*)d_in[7];
    const float* act     = (const float*)d_in[8];
    const float* att     = (const float*)d_in[9];
    const float* rct     = (const float*)d_in[10];
    const float* rit     = (const float*)d_in[11];
    const float* W0      = (const float*)d_in[12];
    const float* W1      = (const float*)d_in[13];

    int n_atoms = in_sizes[1];
    int R       = in_sizes[4];

    float* out     = (float*)d_out;
    float* outBase = out;
    float* outFeat = out + (size_t)R * 3;

    size_t need_bytes = (size_t)(OFF_STARTS + R) * 4;
    if (ws_size >= need_bytes) {
        float* ws     = (float*)d_ws;
        float* Tct    = ws + OFF_TCT;
        float* Trc    = ws + OFF_TRC;
        float* Tri    = ws + OFF_TRI;
        int*   starts = (int*)(ws + OFF_STARTS);

        build_starts<<<(n_atoms + 255) / 256, 256, 0, stream>>>(resIdx, n_atoms, starts);
        int nrows = PAD * NCT + N_RES + MAX_SEQ;  // 4237
        build_tables<<<nrows, OUT0, 0, stream>>>(act, att, rct, rit, W0, Tct, Trc, Tri);
        main_kernel<<<(R + 3) / 4, 256, 0, stream>>>(
            coords, codeIdx, typeIdx, counts, rcIdx, rsIdx, baseIn, W1,
            Tct, Trc, Tri, starts, outBase, outFeat, R);
    } else {
        fallback_kernel<<<R, 128, 0, stream>>>(
            coords, codeIdx, typeIdx, resIdx, counts, rcIdx, rsIdx, baseIn,
            act, att, rct, rit, W0, W1, outBase, outFeat, R, n_atoms);
    }
}

// Round 4
// 141.174 us; speedup vs baseline: 1.2582x; 1.0822x over previous
//
#include <hip/hip_runtime.h>
#include <hip/hip_bf16.h>

// Problem constants (fixed by the reference model definition)
#define PAD        14
#define ACD        32
#define ATD        8
#define RCD        32
#define RID        32
#define N_CODES    38
#define N_TYPES    6
#define NCT        (N_CODES * N_TYPES)   // 228 combined code*6+type rows per slot
#define N_RES      21
#define MAX_SEQ    1024
#define IN0        624     // PAD*ACD + PAD*ATD + RCD + RID
#define OUT0       128
#define OUT1       32      // y1 channels (x3 coords = 96)
#define FEAT       224     // 128 + 96

__device__ __constant__ const float NORM0 = 0.04003203845f;  // 1/sqrt(624)
__device__ __constant__ const float NORM1 = 0.26726124191f;  // 1/sqrt(14)

typedef float f32x2 __attribute__((ext_vector_type(2)));

// ws float offsets
#define SZ_TCT     (PAD * NCT * OUT0)              // 408576 (1.63 MB, L2-resident)
#define OFF_TCT    0
#define OFF_TRC    (OFF_TCT + SZ_TCT)
#define SZ_TRC     (N_RES * OUT0)                  // 2688
#define OFF_TRI    (OFF_TRC + SZ_TRC)
#define SZ_TRI     (MAX_SEQ * OUT0)                // 131072
#define OFF_W1N    (OFF_TRI + SZ_TRI)
#define SZ_W1N     (PAD * OUT1)                    // 448 (W1 * NORM1)
#define OFF_STARTS (OFF_W1N + SZ_W1N)              // ints from here

// ---------------------------------------------------------------------------
// Kernel 1: per-residue start offsets (atoms sorted by residue, count>=1)
// + coalesced base_coords passthrough copy.
__global__ void build_starts(const int* __restrict__ resIdx, int n_atoms,
                             int* __restrict__ starts,
                             const float* __restrict__ baseIn,
                             float* __restrict__ outBase, int nbase) {
    int i = blockIdx.x * blockDim.x + threadIdx.x;
    if (i < nbase) outBase[i] = baseIn[i];
    if (i >= n_atoms) return;
    int r = resIdx[i];
    if (i == 0 || resIdx[i - 1] != r) starts[r] = i;
}

// ---------------------------------------------------------------------------
// Kernel 2: fold W0 through the embedding tables, NORM0 included.
// Combined code+type table: Tct[m][code*6+type][o]. Last block scales W1.
__global__ void build_tables(const float* __restrict__ act, const float* __restrict__ att,
                             const float* __restrict__ rct, const float* __restrict__ rit,
                             const float* __restrict__ W0, const float* __restrict__ W1,
                             float* __restrict__ Tct, float* __restrict__ Trc,
                             float* __restrict__ Tri, float* __restrict__ W1n) {
    int b = blockIdx.x;
    int o = threadIdx.x;  // 128 output channels (coalesced W0 column reads)
    float acc = 0.f;
    if (b < PAD * NCT) {
        int m = b / NCT, ct = b % NCT, c = ct / N_TYPES, t = ct % N_TYPES;
        const float* wc = W0 + (size_t)(m * ACD) * OUT0 + o;
        const float* wt = W0 + (size_t)(PAD * ACD + m * ATD) * OUT0 + o;
#pragma unroll
        for (int j = 0; j < ACD; ++j) acc += act[c * ACD + j] * wc[(size_t)j * OUT0];
#pragma unroll
        for (int j = 0; j < ATD; ++j) acc += att[t * ATD + j] * wt[(size_t)j * OUT0];
        Tct[(size_t)b * OUT0 + o] = acc * NORM0;
    } else if (b < PAD * NCT + N_RES) {
        int c = b - PAD * NCT;
        const float* w = W0 + (size_t)(PAD * ACD + PAD * ATD) * OUT0 + o;
#pragma unroll
        for (int j = 0; j < RCD; ++j) acc += rct[c * RCD + j] * w[(size_t)j * OUT0];
        Trc[(size_t)c * OUT0 + o] = acc * NORM0;
    } else if (b < PAD * NCT + N_RES + MAX_SEQ) {
        int s = b - (PAD * NCT + N_RES);
        const float* w = W0 + (size_t)(PAD * ACD + PAD * ATD + RCD) * OUT0 + o;
#pragma unroll
        for (int j = 0; j < RID; ++j) acc += rit[s * RID + j] * w[(size_t)j * OUT0];
        Tri[(size_t)s * OUT0 + o] = acc * NORM0;
    } else {
        for (int i = o; i < PAD * OUT1; i += OUT0) W1n[i] = W1[i] * NORM1;
    }
}

// ---------------------------------------------------------------------------
// Kernel 3: main. One wave per residue, 4 waves/block, no LDS, no ds ops.
// Prologue: 3 wide per-lane loads stage the residue's raw atom data in VGPRs;
// v_readlane (zero latency) extracts per-atom scalars. Branchless 14-slot loop
// with msk; padded slots clamp to the last real atom -> same gather address ->
// L1 hit. All 14 table gathers issued into t[] BEFORE accumulation (MLP=14).
__global__ __launch_bounds__(256) void main_kernel(
    const float*  __restrict__ coords,   // [n_atoms,3]
    const int*    __restrict__ codeIdx,  // [n_atoms]
    const int*    __restrict__ typeIdx,  // [n_atoms]
    const int*    __restrict__ counts,   // [R]
    const int*    __restrict__ rcIdx,    // [R]
    const int*    __restrict__ rsIdx,    // [R]
    const float*  __restrict__ W1n,      // [14,32] pre-scaled by NORM1
    const float*  __restrict__ Tct, const float* __restrict__ Trc,
    const float*  __restrict__ Tri, const int* __restrict__ starts,
    float* __restrict__ outFeat, int R, int n_atoms) {
    int wid  = threadIdx.x >> 6;
    int lane = threadIdx.x & 63;
    int r = __builtin_amdgcn_readfirstlane(blockIdx.x * 4 + wid);
    if (r >= R) return;

    int start = starts[r];          // wave-uniform scalar loads
    int cnt   = counts[r];
    int rc    = rcIdx[r];
    int rs    = rsIdx[r];
    int lane32 = lane & 31;

    // stage raw atom data across lanes (3 vector loads, clamped for tail safety)
    int ci = 1, ti = 1;
    float crd = 0.f;
    if (lane < PAD) {
        int a = min(start + lane, n_atoms - 1);
        ci = codeIdx[a];
        ti = typeIdx[a];
    }
    if (lane < 3 * PAD) {
        int i3 = min(start * 3 + lane, 3 * n_atoms - 1);
        crd = coords[i3];
    }

    const f32x2* Tct2 = reinterpret_cast<const f32x2*>(Tct);
    const f32x2* Trc2 = reinterpret_cast<const f32x2*>(Trc);
    const f32x2* Tri2 = reinterpret_cast<const f32x2*>(Tri);

    f32x2 a0 = Trc2[(size_t)rc * 64 + lane];
    f32x2 a1 = Tri2[(size_t)rs * 64 + lane];

    int cmax = max(cnt - 1, 0);

    // phase 1: issue ALL table gathers (independent, stay in flight)
    f32x2 t[PAD];
#pragma unroll
    for (int m = 0; m < PAD; ++m) {
        int mm = min(m, cmax);                                   // uniform (SALU)
        int cd = __builtin_amdgcn_readlane(ci, mm);
        int tp = __builtin_amdgcn_readlane(ti, mm);
        t[m] = Tct2[(size_t)(mm * NCT + cd * N_TYPES + tp) * 64 + lane];
    }

    // phase 2: accumulate y0 + y1 (readlane = no memory latency; W1n L1-hot)
    float acx = a0.x + a1.x;
    float acy = a0.y + a1.y;
    float vx = 0.f, vy = 0.f, vz = 0.f;
#pragma unroll
    for (int m = 0; m < PAD; ++m) {
        int mm = min(m, cmax);
        float msk = (m < cnt) ? 1.f : 0.f;                       // uniform
        acx = fmaf(t[m].x, msk, acx);
        acy = fmaf(t[m].y, msk, acy);
        float cx = __uint_as_float(__builtin_amdgcn_readlane(__float_as_uint(crd), 3 * mm + 0));
        float cy = __uint_as_float(__builtin_amdgcn_readlane(__float_as_uint(crd), 3 * mm + 1));
        float cz = __uint_as_float(__builtin_amdgcn_readlane(__float_as_uint(crd), 3 * mm + 2));
        float w  = W1n[m * OUT1 + lane32] * msk;                 // 128B L1-hot row
        vx = fmaf(cx, w, vx);
        vy = fmaf(cy, w, vy);
        vz = fmaf(cz, w, vz);
    }

    float* fo = outFeat + (size_t)r * FEAT;
    f32x2 accv; accv.x = acx; accv.y = acy;
    __builtin_nontemporal_store(accv, reinterpret_cast<f32x2*>(fo) + lane);  // ch 0..127
    if (lane < 32) {
        float* p = fo + OUT0 + 3 * lane32;   // ch 128..223, contiguous across lanes
        __builtin_nontemporal_store(vx, p + 0);
        __builtin_nontemporal_store(vy, p + 1);
        __builtin_nontemporal_store(vz, p + 2);
    }
}

// ---------------------------------------------------------------------------
// Fallback (ws too small): direct per-residue dense dot, binary-search starts.
__global__ __launch_bounds__(128) void fallback_kernel(
    const float* __restrict__ coords, const int* __restrict__ codeIdx,
    const int* __restrict__ typeIdx, const int* __restrict__ resIdx,
    const int* __restrict__ counts, const int* __restrict__ rcIdx,
    const int* __restrict__ rsIdx, const float* __restrict__ baseIn,
    const float* __restrict__ act, const float* __restrict__ att,
    const float* __restrict__ rct, const float* __restrict__ rit,
    const float* __restrict__ W0, const float* __restrict__ W1,
    float* __restrict__ outBase, float* __restrict__ outFeat, int R, int n_atoms) {
    int r = blockIdx.x, tid = threadIdx.x;
    __shared__ float s[IN0];
    __shared__ int sh_start;
    if (tid == 0) {
        int lo = 0, hi = n_atoms;
        while (lo < hi) { int mid = (lo + hi) >> 1; if (resIdx[mid] < r) lo = mid + 1; else hi = mid; }
        sh_start = lo;
    }
    __syncthreads();
    int start = sh_start, cnt = counts[r];
    for (int j = tid; j < IN0; j += 128) {
        float v = 0.f;
        if (j < PAD * ACD) {
            int m = j >> 5, jj = j & 31;
            if (m < cnt) v = act[codeIdx[start + m] * ACD + jj];
        } else if (j < PAD * ACD + PAD * ATD) {
            int t = j - PAD * ACD; int m = t >> 3, jj = t & 7;
            if (m < cnt) v = att[typeIdx[start + m] * ATD + jj];
        } else if (j < PAD * ACD + PAD * ATD + RCD) {
            v = rct[rcIdx[r] * RCD + (j - PAD * ACD - PAD * ATD)];
        } else {
            v = rit[rsIdx[r] * RID + (j - PAD * ACD - PAD * ATD - RCD)];
        }
        s[j] = v;
    }
    __syncthreads();
    float accv = 0.f;
    for (int j = 0; j < IN0; ++j) accv += s[j] * W0[(size_t)j * OUT0 + tid];
    float* fo = outFeat + (size_t)r * FEAT;
    fo[tid] = accv * NORM0;
    if (tid < 96) {
        int n = tid / 3, c = tid % 3;
        float v = 0.f;
        for (int m = 0; m < cnt; ++m) v += coords[(size_t)(start + m) * 3 + c] * W1[m * OUT1 + n];
        fo[OUT0 + tid] = v * NORM1;
    }
    if (tid < 3) outBase[(size_t)r * 3 + tid] = baseIn[(size_t)r * 3 + tid];
}

// ---------------------------------------------------------------------------
extern "C" void kernel_launch(void* const* d_in, const int* in_sizes, int n_in,
                              void* d_out, int out_size, void* d_ws, size_t ws_size,
                              hipStream_t stream) {
    const float* coords = (const float*)d_in[0];
    const int*   codeIdx = (const int*)d_in[1];
    const int*   typeIdx = (const int*)d_in[2];
    const int*   resIdx  = (const int*)d_in[3];
    const int*   counts  = (const int*)d_in[4];
    const int*   rcIdx   = (const int*)d_in[5];
    const int*   rsIdx   = (const int*)d_in[6];
    const float* baseIn  = (const float*)d_in[7];
    const float* act     = (const float*)d_in[8];
    const float* att     = (const float*)d_in[9];
    const float* rct     = (const float*)d_in[10];
    const float* rit     = (const float*)d_in[11];
    const float* W0      = (const float*)d_in[12];
    const float* W1      = (const float*)d_in[13];

    int n_atoms = in_sizes[1];
    int R       = in_sizes[4];

    float* out     = (float*)d_out;
    float* outBase = out;
    float* outFeat = out + (size_t)R * 3;

    size_t need_bytes = (size_t)(OFF_STARTS + R) * 4;
    if (ws_size >= need_bytes) {
        float* ws     = (float*)d_ws;
        float* Tct    = ws + OFF_TCT;
        float* Trc    = ws + OFF_TRC;
        float* Tri    = ws + OFF_TRI;
        float* W1n    = ws + OFF_W1N;
        int*   starts = (int*)(ws + OFF_STARTS);

        build_starts<<<(n_atoms + 255) / 256, 256, 0, stream>>>(
            resIdx, n_atoms, starts, baseIn, outBase, R * 3);
        int nrows = PAD * NCT + N_RES + MAX_SEQ + 1;  // 4238 (last = W1 scale)
        build_tables<<<nrows, OUT0, 0, stream>>>(act, att, rct, rit, W0, W1,
                                                 Tct, Trc, Tri, W1n);
        main_kernel<<<(R + 3) / 4, 256, 0, stream>>>(
            coords, codeIdx, typeIdx, counts, rcIdx, rsIdx, W1n,
            Tct, Trc, Tri, starts, outFeat, R, n_atoms);
    } else {
        fallback_kernel<<<R, 128, 0, stream>>>(
            coords, codeIdx, typeIdx, resIdx, counts, rcIdx, rsIdx, baseIn,
            act, att, rct, rit, W0, W1, outBase, outFeat, R, n_atoms);
    }
}

// Round 5
// 135.121 us; speedup vs baseline: 1.3146x; 1.0448x over previous
//
#include <hip/hip_runtime.h>
#include <hip/hip_bf16.h>

// Problem constants (fixed by the reference model definition)
#define PAD        14
#define ACD        32
#define ATD        8
#define RCD        32
#define RID        32
#define N_CODES    38
#define N_TYPES    6
#define NCT        (N_CODES * N_TYPES)   // 228 combined code*6+type rows per slot
#define N_RES      21
#define MAX_SEQ    1024
#define IN0        624     // PAD*ACD + PAD*ATD + RCD + RID
#define OUT0       128
#define OUT1       32      // y1 channels (x3 coords = 96)
#define FEAT       224     // 128 + 96

// Unified projected-table row space (bf16 rows, 128 ch = 256B each)
#define NROWS_TCT  (PAD * NCT)           // 3192
#define ZROW       NROWS_TCT             // 3192: all-zero row (padded slots)
#define ROW_RC0    (ZROW + 1)            // 3193
#define ROW_RI0    (ROW_RC0 + N_RES)     // 3214
#define NROWS_ALL  (ROW_RI0 + MAX_SEQ)   // 4238

__device__ __constant__ const float NORM0 = 0.04003203845f;  // 1/sqrt(624)
__device__ __constant__ const float NORM1 = 0.26726124191f;  // 1/sqrt(14)

typedef float f32x2 __attribute__((ext_vector_type(2)));

#define SZ_W1N     (PAD * OUT1)          // 448 floats (W1 * NORM1)

// ---- Tier-2 (R4) f32 layout, used only if ws too small for fast path ------
#define T2_SZ_TCT     (PAD * NCT * OUT0)
#define T2_OFF_TCT    0
#define T2_OFF_TRC    (T2_OFF_TCT + T2_SZ_TCT)
#define T2_SZ_TRC     (N_RES * OUT0)
#define T2_OFF_TRI    (T2_OFF_TRC + T2_SZ_TRC)
#define T2_SZ_TRI     (MAX_SEQ * OUT0)
#define T2_OFF_W1N    (T2_OFF_TRI + T2_SZ_TRI)
#define T2_OFF_STARTS (T2_OFF_W1N + SZ_W1N)

// ---------------------------------------------------------------------------
// Kernel 1: per-residue start offsets (atoms sorted by residue, count>=1)
// + coalesced base_coords passthrough copy.
__global__ void build_starts(const int* __restrict__ resIdx, int n_atoms,
                             int* __restrict__ starts,
                             const float* __restrict__ baseIn,
                             float* __restrict__ outBase, int nbase) {
    int i = blockIdx.x * blockDim.x + threadIdx.x;
    if (i < nbase) outBase[i] = baseIn[i];
    if (i >= n_atoms) return;
    int r = resIdx[i];
    if (i == 0 || resIdx[i - 1] != r) starts[r] = i;
}

// ---------------------------------------------------------------------------
// Kernel 2 (fast path): build unified bf16 projected table (NORM0 folded) +
// zero row + W1n. Block b = row id; 128 threads = output channels.
__global__ void build_tall(const float* __restrict__ act, const float* __restrict__ att,
                           const float* __restrict__ rct, const float* __restrict__ rit,
                           const float* __restrict__ W0, const float* __restrict__ W1,
                           __hip_bfloat16* __restrict__ Tall, float* __restrict__ W1n) {
    int b = blockIdx.x;
    int o = threadIdx.x;  // 128 output channels (coalesced W0 column reads)
    float acc = 0.f;
    if (b < NROWS_TCT) {
        int m = b / NCT, ct = b % NCT, c = ct / N_TYPES, t = ct % N_TYPES;
        const float* wc = W0 + (size_t)(m * ACD) * OUT0 + o;
        const float* wt = W0 + (size_t)(PAD * ACD + m * ATD) * OUT0 + o;
#pragma unroll
        for (int j = 0; j < ACD; ++j) acc += act[c * ACD + j] * wc[(size_t)j * OUT0];
#pragma unroll
        for (int j = 0; j < ATD; ++j) acc += att[t * ATD + j] * wt[(size_t)j * OUT0];
        Tall[(size_t)b * OUT0 + o] = __float2bfloat16(acc * NORM0);
    } else if (b == ZROW) {
        Tall[(size_t)b * OUT0 + o] = __float2bfloat16(0.f);
    } else if (b < ROW_RC0 + N_RES) {
        int c = b - ROW_RC0;
        const float* w = W0 + (size_t)(PAD * ACD + PAD * ATD) * OUT0 + o;
#pragma unroll
        for (int j = 0; j < RCD; ++j) acc += rct[c * RCD + j] * w[(size_t)j * OUT0];
        Tall[(size_t)b * OUT0 + o] = __float2bfloat16(acc * NORM0);
    } else if (b < NROWS_ALL) {
        int s = b - ROW_RI0;
        const float* w = W0 + (size_t)(PAD * ACD + PAD * ATD + RCD) * OUT0 + o;
#pragma unroll
        for (int j = 0; j < RID; ++j) acc += rit[s * RID + j] * w[(size_t)j * OUT0];
        Tall[(size_t)b * OUT0 + o] = __float2bfloat16(acc * NORM0);
    } else {
        for (int i = o; i < PAD * OUT1; i += OUT0) W1n[i] = W1[i] * NORM1;
    }
}

// ---------------------------------------------------------------------------
// Kernel 3 (fast path): per-residue meta record, atom-parallel build.
// meta[r] = 64 ints (256B): [0..15] table row ids (padded slots -> ZROW,
// slot14 = Trc row, slot15 = Tri row); floats [16..29]=x, [32..45]=y,
// [48..61]=z transposed coords, zero-padded.
__global__ void build_meta(const int* __restrict__ starts, const int* __restrict__ counts,
                           const int* __restrict__ codeIdx, const int* __restrict__ typeIdx,
                           const float* __restrict__ coords,
                           const int* __restrict__ rcIdx, const int* __restrict__ rsIdx,
                           int* __restrict__ meta, int R) {
    int gid = blockIdx.x * blockDim.x + threadIdx.x;
    int r = gid >> 4, slot = gid & 15;
    if (r >= R) return;
    int* mp = meta + (size_t)r * 64;
    float* mpf = (float*)mp;
    if (slot < PAD) {
        int cnt = counts[r];
        int row = ZROW;
        float cx = 0.f, cy = 0.f, cz = 0.f;
        if (slot < cnt) {
            int a = starts[r] + slot;
            row = slot * NCT + codeIdx[a] * N_TYPES + typeIdx[a];
            cx = coords[3 * (size_t)a + 0];
            cy = coords[3 * (size_t)a + 1];
            cz = coords[3 * (size_t)a + 2];
        }
        mp[slot] = row;
        mpf[16 + slot] = cx;
        mpf[32 + slot] = cy;
        mpf[48 + slot] = cz;
    } else if (slot == 14) {
        mp[14] = ROW_RC0 + rcIdx[r];
    } else {
        mp[15] = ROW_RI0 + rsIdx[r];
    }
}

// ---------------------------------------------------------------------------
// Kernel 4 (fast path): straightline main. Grid-stride persistent waves, one
// residue per wave-iteration. Metadata via 4 scalar-cache loads; 16
// unconditional bf16-row gathers (u32/lane = 2 channels); zero-row absorbs
// padding (L1-hot). W1n lives in 14 VGPRs for the whole wave. No LDS, no
// shuffles, no masks, no branches in the residue body.
__global__ __launch_bounds__(256) void main_fast(
    const int* __restrict__ meta,
    const unsigned int* __restrict__ Tall,   // u32 view of bf16 rows
    const float* __restrict__ W1n,
    float* __restrict__ outFeat, int R) {
    int lane   = threadIdx.x & 63;
    int lane32 = lane & 31;
    int wgid = (blockIdx.x * 256 + threadIdx.x) >> 6;
    int nwv  = (gridDim.x * 256) >> 6;

    float w14[PAD];
#pragma unroll
    for (int m = 0; m < PAD; ++m) w14[m] = W1n[m * OUT1 + lane32];

    for (int r0 = wgid; r0 < R; r0 += nwv) {
        int r = __builtin_amdgcn_readfirstlane(r0);
        const int*   mp  = meta + (size_t)r * 64;
        const float* mpf = (const float*)mp;

        int rw[16];
#pragma unroll
        for (int j = 0; j < 16; ++j) rw[j] = mp[j];          // SMEM

        unsigned int t[16];
#pragma unroll
        for (int j = 0; j < 16; ++j)
            t[j] = Tall[(size_t)rw[j] * 64 + lane];          // 16 gathers in flight

        float vx = 0.f, vy = 0.f, vz = 0.f;
#pragma unroll
        for (int m = 0; m < PAD; ++m) {                      // SGPR coord x VGPR w
            vx = fmaf(mpf[16 + m], w14[m], vx);
            vy = fmaf(mpf[32 + m], w14[m], vy);
            vz = fmaf(mpf[48 + m], w14[m], vz);
        }

        float acx = 0.f, acy = 0.f;
#pragma unroll
        for (int j = 0; j < 16; ++j) {                       // bf16 pair unpack+add
            acx += __uint_as_float(t[j] << 16);
            acy += __uint_as_float(t[j] & 0xffff0000u);
        }

        float* fo = outFeat + (size_t)r * FEAT;
        f32x2 v2; v2.x = acx; v2.y = acy;
        __builtin_nontemporal_store(v2, reinterpret_cast<f32x2*>(fo) + lane);  // ch 0..127
        if (lane < 32) {
            float* p = fo + OUT0 + 3 * lane32;               // ch 128..223
            __builtin_nontemporal_store(vx, p + 0);
            __builtin_nontemporal_store(vy, p + 1);
            __builtin_nontemporal_store(vz, p + 2);
        }
    }
}

// ---------------------------------------------------------------------------
// Tier-2 (R4 fast kernel, f32 tables) — used only when ws < fast-path need.
__global__ void build_tables_t2(const float* __restrict__ act, const float* __restrict__ att,
                                const float* __restrict__ rct, const float* __restrict__ rit,
                                const float* __restrict__ W0, const float* __restrict__ W1,
                                float* __restrict__ Tct, float* __restrict__ Trc,
                                float* __restrict__ Tri, float* __restrict__ W1n) {
    int b = blockIdx.x;
    int o = threadIdx.x;
    float acc = 0.f;
    if (b < PAD * NCT) {
        int m = b / NCT, ct = b % NCT, c = ct / N_TYPES, t = ct % N_TYPES;
        const float* wc = W0 + (size_t)(m * ACD) * OUT0 + o;
        const float* wt = W0 + (size_t)(PAD * ACD + m * ATD) * OUT0 + o;
#pragma unroll
        for (int j = 0; j < ACD; ++j) acc += act[c * ACD + j] * wc[(size_t)j * OUT0];
#pragma unroll
        for (int j = 0; j < ATD; ++j) acc += att[t * ATD + j] * wt[(size_t)j * OUT0];
        Tct[(size_t)b * OUT0 + o] = acc * NORM0;
    } else if (b < PAD * NCT + N_RES) {
        int c = b - PAD * NCT;
        const float* w = W0 + (size_t)(PAD * ACD + PAD * ATD) * OUT0 + o;
#pragma unroll
        for (int j = 0; j < RCD; ++j) acc += rct[c * RCD + j] * w[(size_t)j * OUT0];
        Trc[(size_t)c * OUT0 + o] = acc * NORM0;
    } else if (b < PAD * NCT + N_RES + MAX_SEQ) {
        int s = b - (PAD * NCT + N_RES);
        const float* w = W0 + (size_t)(PAD * ACD + PAD * ATD + RCD) * OUT0 + o;
#pragma unroll
        for (int j = 0; j < RID; ++j) acc += rit[s * RID + j] * w[(size_t)j * OUT0];
        Tri[(size_t)s * OUT0 + o] = acc * NORM0;
    } else {
        for (int i = o; i < PAD * OUT1; i += OUT0) W1n[i] = W1[i] * NORM1;
    }
}

__global__ __launch_bounds__(256) void main_t2(
    const float*  __restrict__ coords, const int* __restrict__ codeIdx,
    const int*    __restrict__ typeIdx, const int* __restrict__ counts,
    const int*    __restrict__ rcIdx, const int* __restrict__ rsIdx,
    const float*  __restrict__ W1n,
    const float*  __restrict__ Tct, const float* __restrict__ Trc,
    const float*  __restrict__ Tri, const int* __restrict__ starts,
    float* __restrict__ outFeat, int R, int n_atoms) {
    int wid  = threadIdx.x >> 6;
    int lane = threadIdx.x & 63;
    int r = __builtin_amdgcn_readfirstlane(blockIdx.x * 4 + wid);
    if (r >= R) return;
    int start = starts[r];
    int cnt   = counts[r];
    int rc    = rcIdx[r];
    int rs    = rsIdx[r];
    int lane32 = lane & 31;
    int ci = 1, ti = 1;
    float crd = 0.f;
    if (lane < PAD) {
        int a = min(start + lane, n_atoms - 1);
        ci = codeIdx[a];
        ti = typeIdx[a];
    }
    if (lane < 3 * PAD) {
        int i3 = min(start * 3 + lane, 3 * n_atoms - 1);
        crd = coords[i3];
    }
    const f32x2* Tct2 = reinterpret_cast<const f32x2*>(Tct);
    const f32x2* Trc2 = reinterpret_cast<const f32x2*>(Trc);
    const f32x2* Tri2 = reinterpret_cast<const f32x2*>(Tri);
    f32x2 a0 = Trc2[(size_t)rc * 64 + lane];
    f32x2 a1 = Tri2[(size_t)rs * 64 + lane];
    int cmax = max(cnt - 1, 0);
    f32x2 t[PAD];
#pragma unroll
    for (int m = 0; m < PAD; ++m) {
        int mm = min(m, cmax);
        int cd = __builtin_amdgcn_readlane(ci, mm);
        int tp = __builtin_amdgcn_readlane(ti, mm);
        t[m] = Tct2[(size_t)(mm * NCT + cd * N_TYPES + tp) * 64 + lane];
    }
    float acx = a0.x + a1.x;
    float acy = a0.y + a1.y;
    float vx = 0.f, vy = 0.f, vz = 0.f;
#pragma unroll
    for (int m = 0; m < PAD; ++m) {
        int mm = min(m, cmax);
        float msk = (m < cnt) ? 1.f : 0.f;
        acx = fmaf(t[m].x, msk, acx);
        acy = fmaf(t[m].y, msk, acy);
        float cx = __uint_as_float(__builtin_amdgcn_readlane(__float_as_uint(crd), 3 * mm + 0));
        float cy = __uint_as_float(__builtin_amdgcn_readlane(__float_as_uint(crd), 3 * mm + 1));
        float cz = __uint_as_float(__builtin_amdgcn_readlane(__float_as_uint(crd), 3 * mm + 2));
        float w  = W1n[m * OUT1 + lane32] * msk;
        vx = fmaf(cx, w, vx);
        vy = fmaf(cy, w, vy);
        vz = fmaf(cz, w, vz);
    }
    float* fo = outFeat + (size_t)r * FEAT;
    f32x2 accv; accv.x = acx; accv.y = acy;
    __builtin_nontemporal_store(accv, reinterpret_cast<f32x2*>(fo) + lane);
    if (lane < 32) {
        float* p = fo + OUT0 + 3 * lane32;
        __builtin_nontemporal_store(vx, p + 0);
        __builtin_nontemporal_store(vy, p + 1);
        __builtin_nontemporal_store(vz, p + 2);
    }
}

// ---------------------------------------------------------------------------
// Tier-3 fallback (tiny ws): direct per-residue dense dot.
__global__ __launch_bounds__(128) void fallback_kernel(
    const float* __restrict__ coords, const int* __restrict__ codeIdx,
    const int* __restrict__ typeIdx, const int* __restrict__ resIdx,
    const int* __restrict__ counts, const int* __restrict__ rcIdx,
    const int* __restrict__ rsIdx, const float* __restrict__ baseIn,
    const float* __restrict__ act, const float* __restrict__ att,
    const float* __restrict__ rct, const float* __restrict__ rit,
    const float* __restrict__ W0, const float* __restrict__ W1,
    float* __restrict__ outBase, float* __restrict__ outFeat, int R, int n_atoms) {
    int r = blockIdx.x, tid = threadIdx.x;
    __shared__ float s[IN0];
    __shared__ int sh_start;
    if (tid == 0) {
        int lo = 0, hi = n_atoms;
        while (lo < hi) { int mid = (lo + hi) >> 1; if (resIdx[mid] < r) lo = mid + 1; else hi = mid; }
        sh_start = lo;
    }
    __syncthreads();
    int start = sh_start, cnt = counts[r];
    for (int j = tid; j < IN0; j += 128) {
        float v = 0.f;
        if (j < PAD * ACD) {
            int m = j >> 5, jj = j & 31;
            if (m < cnt) v = act[codeIdx[start + m] * ACD + jj];
        } else if (j < PAD * ACD + PAD * ATD) {
            int t = j - PAD * ACD; int m = t >> 3, jj = t & 7;
            if (m < cnt) v = att[typeIdx[start + m] * ATD + jj];
        } else if (j < PAD * ACD + PAD * ATD + RCD) {
            v = rct[rcIdx[r] * RCD + (j - PAD * ACD - PAD * ATD)];
        } else {
            v = rit[rsIdx[r] * RID + (j - PAD * ACD - PAD * ATD - RCD)];
        }
        s[j] = v;
    }
    __syncthreads();
    float accv = 0.f;
    for (int j = 0; j < IN0; ++j) accv += s[j] * W0[(size_t)j * OUT0 + tid];
    float* fo = outFeat + (size_t)r * FEAT;
    fo[tid] = accv * NORM0;
    if (tid < 96) {
        int n = tid / 3, c = tid % 3;
        float v = 0.f;
        for (int m = 0; m < cnt; ++m) v += coords[(size_t)(start + m) * 3 + c] * W1[m * OUT1 + n];
        fo[OUT0 + tid] = v * NORM1;
    }
    if (tid < 3) outBase[(size_t)r * 3 + tid] = baseIn[(size_t)r * 3 + tid];
}

// ---------------------------------------------------------------------------
extern "C" void kernel_launch(void* const* d_in, const int* in_sizes, int n_in,
                              void* d_out, int out_size, void* d_ws, size_t ws_size,
                              hipStream_t stream) {
    const float* coords = (const float*)d_in[0];
    const int*   codeIdx = (const int*)d_in[1];
    const int*   typeIdx = (const int*)d_in[2];
    const int*   resIdx  = (const int*)d_in[3];
    const int*   counts  = (const int*)d_in[4];
    const int*   rcIdx   = (const int*)d_in[5];
    const int*   rsIdx   = (const int*)d_in[6];
    const float* baseIn  = (const float*)d_in[7];
    const float* act     = (const float*)d_in[8];
    const float* att     = (const float*)d_in[9];
    const float* rct     = (const float*)d_in[10];
    const float* rit     = (const float*)d_in[11];
    const float* W0      = (const float*)d_in[12];
    const float* W1      = (const float*)d_in[13];

    int n_atoms = in_sizes[1];
    int R       = in_sizes[4];

    float* out     = (float*)d_out;
    float* outBase = out;
    float* outFeat = out + (size_t)R * 3;

    // fast-path ws layout (bytes)
    size_t tallBytes = (size_t)NROWS_ALL * OUT0 * 2;            // bf16 rows
    size_t w1nOff    = tallBytes;
    size_t startsOff = w1nOff + (size_t)SZ_W1N * 4;
    size_t metaOff   = (startsOff + (size_t)R * 4 + 255) & ~(size_t)255;
    size_t needFast  = metaOff + (size_t)R * 256;
    size_t needT2    = (size_t)(T2_OFF_STARTS + R) * 4;

    if (ws_size >= needFast) {
        char* wsb = (char*)d_ws;
        __hip_bfloat16* Tall   = (__hip_bfloat16*)wsb;
        unsigned int*   TallU  = (unsigned int*)wsb;
        float*          W1n    = (float*)(wsb + w1nOff);
        int*            starts = (int*)(wsb + startsOff);
        int*            meta   = (int*)(wsb + metaOff);

        build_starts<<<(n_atoms + 255) / 256, 256, 0, stream>>>(
            resIdx, n_atoms, starts, baseIn, outBase, R * 3);
        build_tall<<<NROWS_ALL + 1, OUT0, 0, stream>>>(
            act, att, rct, rit, W0, W1, Tall, W1n);
        build_meta<<<((size_t)R * 16 + 255) / 256, 256, 0, stream>>>(
            starts, counts, codeIdx, typeIdx, coords, rcIdx, rsIdx, meta, R);
        main_fast<<<2048, 256, 0, stream>>>(meta, TallU, W1n, outFeat, R);
    } else if (ws_size >= needT2) {
        float* ws     = (float*)d_ws;
        float* Tct    = ws + T2_OFF_TCT;
        float* Trc    = ws + T2_OFF_TRC;
        float* Tri    = ws + T2_OFF_TRI;
        float* W1n    = ws + T2_OFF_W1N;
        int*   starts = (int*)(ws + T2_OFF_STARTS);
        build_starts<<<(n_atoms + 255) / 256, 256, 0, stream>>>(
            resIdx, n_atoms, starts, baseIn, outBase, R * 3);
        int nrows = PAD * NCT + N_RES + MAX_SEQ + 1;
        build_tables_t2<<<nrows, OUT0, 0, stream>>>(act, att, rct, rit, W0, W1,
                                                    Tct, Trc, Tri, W1n);
        main_t2<<<(R + 3) / 4, 256, 0, stream>>>(
            coords, codeIdx, typeIdx, counts, rcIdx, rsIdx, W1n,
            Tct, Trc, Tri, starts, outFeat, R, n_atoms);
    } else {
        fallback_kernel<<<R, 128, 0, stream>>>(
            coords, codeIdx, typeIdx, resIdx, counts, rcIdx, rsIdx, baseIn,
            act, att, rct, rit, W0, W1, outBase, outFeat, R, n_atoms);
    }
}